// Round 5
// baseline (6056.056 us; speedup 1.0000x reference)
//
#include <hip/hip_runtime.h>
#include <math.h>

// NodeformerProcessor: 3x (nodeformer_conv -> [leaky] -> graph_norm), full fp64.
// v5: dd = DN*(x @ (W@P^T) + b@P^T) via per-layer precomputed WP (f64) ->
//     k_kv drops ks from LDS entirely (k lives in registers for the diag
//     butterfly only); k_q is per-head with small LDS. All hot LDS rows
//     padded to 65 doubles (v4 had 4.2e7 bank conflicts from 64-aligned
//     rows). 3 blocks/CU on the two big kernels, 8-way FMA chain ILP.
//     absmax proven insensitive to fp64 reordering (bit-identical v1-v4).

namespace {

constexpr int N   = 50000;
constexpr int C   = 64;
constexpr int H   = 8;
constexpr int HD  = 512;
constexpr int M   = 30;

constexpr int NT2 = 8;             // nodes/group in k_kv
constexpr int NG2 = N / NT2;       // 6250
constexpr int NB2 = 96;            // blocks per head in k_kv (grid 768 = 3/CU)
constexpr int PSTR = 2016;         // partial: A[0..1920) | Es@1920 | Sv@1950 | max@2014

constexpr int ROUNDS = 5;
constexpr int RNODES = N / ROUNDS; // 10000
constexpr int NGQ    = RNODES / 8; // 1250 groups of 8 per head (k_q)
constexpr int NBQH   = 96;         // blocks per head in k_q (grid 768)
constexpr int NBY    = 512;        // k_y grid / psum rows

__device__ constexpr double DN    = 0.35355339059327373;  // 1/sqrt(sqrt(64))
__device__ constexpr double RATIO = 0.18257418583505536;  // 1/sqrt(30)
__device__ constexpr double EPSK  = 1e-6;
__device__ constexpr double EPSN  = 1e-5;

__device__ __forceinline__ void kah(double& s, double& c, double v) {
  double y = v - c; double t = s + y; c = (t - s) - y; s = t;
}

// -------- pass 0: WP[side][h][m][c] = DN * sum_d W[c][h*64+d] * P[m][d] --------
__global__ __launch_bounds__(256)
void k_wp(const float* __restrict__ Wk, const float* __restrict__ bk,
          const float* __restrict__ Wq, const float* __restrict__ bq,
          const float* __restrict__ P, double* __restrict__ wp,
          double* __restrict__ bp) {
  const int blk = blockIdx.x, side = blk >> 3, h = blk & 7, t = threadIdx.x;
  const float* W  = side ? Wq : Wk;
  const float* bb = side ? bq : bk;
  for (int s = t; s < 1920; s += 256) {
    const int m = s >> 6, c = s & 63;
    double a = 0.0;
    for (int d = 0; d < 64; ++d)
      a = fma((double)W[c * HD + h * 64 + d], (double)P[m * 64 + d], a);
    wp[((size_t)(side * 8 + h) * 30 + m) * 64 + c] = a * DN;
  }
  if (t < 30) {
    double a = 0.0;
    for (int d = 0; d < 64; ++d)
      a = fma((double)bb[h * 64 + d], (double)P[t * 64 + d], a);
    bp[(side * 8 + h) * 30 + t] = a * DN;
  }
}

// ---------------- pass 1: per-head A/Es/Sv partials + max(dd) ----------------
template <int LM>  // 0: x from f32 source; 1: x = (y - a)*b + c (norm fold)
__global__ __launch_bounds__(256, 3)
void k_kv(const float* __restrict__ xf, const double* __restrict__ yv,
          const double* __restrict__ nparam,
          const float* __restrict__ Wk, const float* __restrict__ bk,
          const float* __restrict__ Wv, const float* __restrict__ bv,
          const double* __restrict__ wp, const double* __restrict__ bp,
          double* __restrict__ partial) {
  __shared__ float  wvs[4096];          // Wv slice [c][j] for this head
  __shared__ double wpk[30 * 65];       // WP_k rows, padded
  __shared__ double xs[8 * 65];         // x, padded rows (also final scratch)
  __shared__ double vsd[8 * 65];        // v, padded rows (also final scratch)
  __shared__ double kplR[240];          // raw dd
  __shared__ double kplV[240];          // exp values
  __shared__ double diag[8];
  __shared__ double bpk[30];
  const int t = threadIdx.x, i0 = t >> 6, c0 = t & 63;
  const int h = blockIdx.x / NB2, b = blockIdx.x % NB2, hb = h * 64;

  for (int s = t; s < 4096; s += 256)
    wvs[s] = Wv[(s >> 6) * HD + hb + (s & 63)];
  for (int s = t; s < 1920; s += 256)
    wpk[(s >> 6) * 65 + (s & 63)] = wp[(size_t)h * 1920 + s];
  if (t < 30) bpk[t] = bp[h * 30 + t];
  const double bk0 = (double)bk[hb + c0], bv0 = (double)bv[hb + c0];
  double npa = 0, npb = 0, npc = 0;
  if (LM == 1) { npa = nparam[c0]; npb = nparam[64 + c0]; npc = nparam[128 + c0]; }
  double acc8[8];
#pragma unroll
  for (int k = 0; k < 8; ++k) acc8[k] = 0.0;
  double ssv = 0, ses = 0, runmax = -1e300;
  const int di = (t < 240) ? t / 30 : 0;
  const int dm = (t < 240) ? t - di * 30 : 0;
  __syncthreads();

  for (int g = b; g < NG2; g += NB2) {
    const int n0 = g * NT2;
    {
      const size_t gi0 = (size_t)(n0 + i0) * C + c0;
      const size_t gi1 = (size_t)(n0 + i0 + 4) * C + c0;
      double x0, x1;
      if (LM == 0) { x0 = (double)xf[gi0]; x1 = (double)xf[gi1]; }
      else {
        x0 = (yv[gi0] - npa) * npb + npc;
        x1 = (yv[gi1] - npa) * npb + npc;
      }
      xs[i0 * 65 + c0] = x0; xs[(i0 + 4) * 65 + c0] = x1;
    }
    __syncthreads();
    // k,v projection: 2 nodes/thread, 8 independent fma chains
    double kaA = bk0, kaB = 0.0, k1A = bk0, k1B = 0.0;
    double vaA = bv0, vaB = 0.0, v1A = bv0, v1B = 0.0;
#pragma unroll 8
    for (int c = 0; c < 32; ++c) {
      const double x0a = xs[i0 * 65 + c],       x0b = xs[i0 * 65 + c + 32];
      const double x1a = xs[(i0 + 4) * 65 + c], x1b = xs[(i0 + 4) * 65 + c + 32];
      const double wka = (double)Wk[c * HD + hb + c0];
      const double wkb = (double)Wk[(c + 32) * HD + hb + c0];
      const double wva = (double)wvs[c * 64 + c0];
      const double wvb = (double)wvs[(c + 32) * 64 + c0];
      kaA = fma(x0a, wka, kaA); kaB = fma(x0b, wkb, kaB);
      k1A = fma(x1a, wka, k1A); k1B = fma(x1b, wkb, k1B);
      vaA = fma(x0a, wva, vaA); vaB = fma(x0b, wvb, vaB);
      v1A = fma(x1a, wva, v1A); v1B = fma(x1b, wvb, v1B);
    }
    const double ka0 = kaA + kaB, ka1 = k1A + k1B;
    const double va0 = vaA + vaB, va1 = v1A + v1B;
    vsd[i0 * 65 + c0] = va0; vsd[(i0 + 4) * 65 + c0] = va1;
    // diag via wave butterfly
    double q0 = ka0 * ka0, q1 = ka1 * ka1;
#pragma unroll
    for (int off = 32; off; off >>= 1) {
      q0 += __shfl_xor(q0, off, 64);
      q1 += __shfl_xor(q1, off, 64);
    }
    if (c0 == 0) { diag[i0] = q0 * (DN * DN * 0.5); diag[i0 + 4] = q1 * (DN * DN * 0.5); }
    ssv += va0 + va1;
    // dd_k straight from x via WP (no ks needed)
    if (t < 240) {
      double a = bpk[dm];
#pragma unroll 8
      for (int c = 0; c < 64; ++c)
        a = fma(xs[di * 65 + c], wpk[dm * 65 + c], a);
      kplR[t] = a;
    }
    __syncthreads();
    if (t < 240) {
      const double raw = kplR[t];
      runmax = fmax(runmax, raw);
      kplV[t] = exp(raw - diag[di]);
    }
    __syncthreads();
    if (t < 30) {  // Es[m] partial
      double gsum = 0.0;
#pragma unroll
      for (int i = 0; i < NT2; ++i) gsum += kplV[i * 30 + t];
      ses += gsum;
    }
    // A[m][d] += E[i][m]*v[i][d]
#pragma unroll
    for (int k = 0; k < 8; ++k) {
      const int s = t + (k << 8);
      if (s < 1920) {
        const int m = s >> 6;
        double gsum = acc8[k];
#pragma unroll
        for (int i = 0; i < NT2; ++i)
          gsum = fma(kplV[i * 30 + m], vsd[i * 65 + c0], gsum);
        acc8[k] = gsum;
      }
    }
    __syncthreads();
  }
  // block-level outputs (reuse xs / vsd as scratch)
  const size_t base = (size_t)blockIdx.x * PSTR;
  xs[t] = ssv;
  vsd[t] = runmax;
  __syncthreads();
  if (t < 64) partial[base + 1950 + t] = xs[t] + xs[t + 64] + xs[t + 128] + xs[t + 192];
  for (int off = 128; off; off >>= 1) {
    if (t < off) vsd[t] = fmax(vsd[t], vsd[t + off]);
    __syncthreads();
  }
  if (t == 0) partial[base + 2014] = vsd[0];
  if (t < M) partial[base + 1920 + t] = ses;
#pragma unroll
  for (int k = 0; k < 8; ++k) {
    const int s = t + (k << 8);
    if (s < 1920) partial[base + s] = acc8[k];
  }
}

// ------- pass 2: reduce partials, apply stab/eps, precompute G = kvs@Wo -------
__global__ __launch_bounds__(256)
void k_redkv(const double* __restrict__ partial, const float* __restrict__ Wo,
             double* __restrict__ ksumg, double* __restrict__ Gg) {
  const int h = blockIdx.x, t = threadIdx.x;
  __shared__ double red[128];
  __shared__ double svt[64];
  __shared__ double kvls[M * 64];
  __shared__ double escs;
  const size_t hb = (size_t)h * NB2;
  if (t < 128) red[t] = (t < NB2) ? partial[(hb + t) * PSTR + 2014] : -1e300;
  __syncthreads();
  for (int off = 64; off; off >>= 1) {
    if (t < off) red[t] = fmax(red[t], red[t + off]);
    __syncthreads();
  }
  if (t == 0) escs = exp(-red[0]);
  __syncthreads();
  const double esc = escs;
  if (t < 64) {
    double s = 0, c = 0;
    for (int b = 0; b < NB2; ++b) kah(s, c, partial[(hb + b) * PSTR + 1950 + t]);
    svt[t] = s - c;
  } else if (t < 64 + M) {
    const int m = t - 64;
    double s = 0, c = 0;
    for (int b = 0; b < NB2; ++b) kah(s, c, partial[(hb + b) * PSTR + 1920 + m]);
    ksumg[h * M + m] = RATIO * (esc * (s - c) + EPSK * (double)N);
  }
  __syncthreads();
#pragma unroll
  for (int k = 0; k < 8; ++k) {
    const int sidx = t + (k << 8);
    if (sidx < M * 64) {
      double s = 0, c = 0;
      for (int b = 0; b < NB2; ++b) kah(s, c, partial[(hb + b) * PSTR + sidx]);
      kvls[sidx] = RATIO * (esc * (s - c) + EPSK * svt[sidx & 63]);
    }
  }
  __syncthreads();
  // G[m][c] = sum_d kvs[m][d] * Wo[(h*64+d)*64 + c]
#pragma unroll
  for (int k = 0; k < 8; ++k) {
    const int sidx = t + (k << 8);
    if (sidx < M * 64) {
      const int m = sidx >> 6, c = sidx & 63;
      double a = 0.0;
      for (int d = 0; d < 64; ++d)
        a = fma(kvls[m * 64 + d], (double)Wo[(h * 64 + d) * 64 + c], a);
      Gg[(size_t)h * (M * 64) + sidx] = a;
    }
  }
}

// ------- pass 3a: per-head qp' = qp/den for a node-fifth ----------------------
template <int LM>
__global__ __launch_bounds__(256, 3)
void k_q(const float* __restrict__ xf, const double* __restrict__ yv,
         const double* __restrict__ nparam,
         const float* __restrict__ Wq, const float* __restrict__ bq,
         const double* __restrict__ wp, const double* __restrict__ bp,
         const double* __restrict__ ksumg,
         double* __restrict__ qpq, int rbase) {
  __shared__ double wpq[30 * 65];
  __shared__ double xs[8 * 65];
  __shared__ double qpsR[240];
  __shared__ double qpsV[240];
  __shared__ double diag[8];
  __shared__ double ksl[30];
  __shared__ double bpq[30];
  const int t = threadIdx.x, i0 = t >> 6, c0 = t & 63;
  const int h = blockIdx.x / NBQH, b = blockIdx.x % NBQH, hb = h * 64;

  for (int s = t; s < 1920; s += 256)
    wpq[(s >> 6) * 65 + (s & 63)] = wp[(size_t)(8 + h) * 1920 + s];
  if (t < 30) { bpq[t] = bp[(8 + h) * 30 + t]; ksl[t] = ksumg[h * 30 + t]; }
  const double bq0 = (double)bq[hb + c0];
  double npa = 0, npb = 0, npc = 0;
  if (LM == 1) { npa = nparam[c0]; npb = nparam[64 + c0]; npc = nparam[128 + c0]; }
  const int di = (t < 240) ? t / 30 : 0;
  const int dm = (t < 240) ? t - di * 30 : 0;
  __syncthreads();

  for (int g = b; g < NGQ; g += NBQH) {
    const int n0 = rbase + g * 8;
    {
      const size_t gi0 = (size_t)(n0 + i0) * C + c0;
      const size_t gi1 = (size_t)(n0 + i0 + 4) * C + c0;
      double x0, x1;
      if (LM == 0) { x0 = (double)xf[gi0]; x1 = (double)xf[gi1]; }
      else {
        x0 = (yv[gi0] - npa) * npb + npc;
        x1 = (yv[gi1] - npa) * npb + npc;
      }
      xs[i0 * 65 + c0] = x0; xs[(i0 + 4) * 65 + c0] = x1;
    }
    __syncthreads();
    // q projection (only needed for diag), 4 chains
    double qA = bq0, qB = 0.0, q1A = bq0, q1B = 0.0;
#pragma unroll 8
    for (int c = 0; c < 32; ++c) {
      const double x0a = xs[i0 * 65 + c],       x0b = xs[i0 * 65 + c + 32];
      const double x1a = xs[(i0 + 4) * 65 + c], x1b = xs[(i0 + 4) * 65 + c + 32];
      const double wqa = (double)Wq[c * HD + hb + c0];
      const double wqb = (double)Wq[(c + 32) * HD + hb + c0];
      qA  = fma(x0a, wqa, qA);  qB  = fma(x0b, wqb, qB);
      q1A = fma(x1a, wqa, q1A); q1B = fma(x1b, wqb, q1B);
    }
    const double qa0 = qA + qB, qa1 = q1A + q1B;
    double s0 = qa0 * qa0, s1 = qa1 * qa1;
#pragma unroll
    for (int off = 32; off; off >>= 1) {
      s0 += __shfl_xor(s0, off, 64);
      s1 += __shfl_xor(s1, off, 64);
    }
    if (c0 == 0) { diag[i0] = s0 * (DN * DN * 0.5); diag[i0 + 4] = s1 * (DN * DN * 0.5); }
    // dd_q from x via WP
    if (t < 240) {
      double a = bpq[dm];
#pragma unroll 8
      for (int c = 0; c < 64; ++c)
        a = fma(xs[di * 65 + c], wpq[dm * 65 + c], a);
      qpsR[t] = a;
    }
    __syncthreads();
    if (t < 240) {  // per-(n): stab = max over m (redundant scan, broadcast reads)
      double mx = qpsR[di * 30];
      for (int m = 1; m < 30; ++m) mx = fmax(mx, qpsR[di * 30 + m]);
      qpsV[t] = RATIO * (exp((qpsR[t] - diag[di]) - mx) + EPSK);
    }
    __syncthreads();
    if (t < 240) {  // den (redundant per i), write qp'/den
      double den = 0.0;
      for (int m = 0; m < 30; ++m) den = fma(qpsV[di * 30 + m], ksl[m], den);
      qpq[(size_t)(n0 + di - rbase) * 240 + h * 30 + dm] = qpsV[t] / den;
    }
    __syncthreads();
  }
}

// ------- pass 3b: y = bo + qp' @ G (G LDS-resident), leaky, column sums -------
__global__ __launch_bounds__(1024, 1)
void k_y(const double* __restrict__ qpq, const double* __restrict__ Gg,
         const float* __restrict__ bo, int do_leaky,
         double* __restrict__ y, double* __restrict__ psum,
         int rbase, int round) {
  extern __shared__ double sm[];
  double* Gl  = sm;            // 240*64 = 15360
  double* qpl = sm + 15360;    // 32*120 = 3840 (also reused for reductions)
  const int t = threadIdx.x, i0 = t >> 6, c0 = t & 63;
  for (int s = t; s < 15360; s += 1024) Gl[s] = Gg[s];
  const double bo0 = (double)bo[c0];
  const int rend = rbase + RNODES;
  double sy = 0, sy2 = 0;
  __syncthreads();

  const int nchunks = (RNODES + 31) / 32;
  for (int ch = blockIdx.x; ch < nchunks; ch += gridDim.x) {
    const int base = rbase + ch * 32;
    const int na = base + i0, nb = base + 16 + i0;
    double acca = bo0, accb = bo0;
    for (int ph = 0; ph < 2; ++ph) {
      __syncthreads();
      for (int s = t; s < 3840; s += 1024) {
        const int ni = s / 120, jj = s - ni * 120;
        const int n = base + ni;
        qpl[s] = (n < rend) ? qpq[(size_t)(n - rbase) * 240 + ph * 120 + jj] : 0.0;
      }
      __syncthreads();
      const double* qa = qpl + i0 * 120;
      const double* qb = qpl + (16 + i0) * 120;
      const double* gl = Gl + ph * 120 * 64 + c0;
      for (int j = 0; j < 120; ++j) {
        const double gv = gl[(size_t)j * 64];
        acca = fma(qa[j], gv, acca);
        accb = fma(qb[j], gv, accb);
      }
    }
    if (do_leaky) {
      acca = (acca >= 0.0) ? acca : 0.01 * acca;
      accb = (accb >= 0.0) ? accb : 0.01 * accb;
    }
    if (na < rend) { y[(size_t)na * C + c0] = acca; sy += acca; sy2 = fma(acca, acca, sy2); }
    if (nb < rend) { y[(size_t)nb * C + c0] = accb; sy += accb; sy2 = fma(accb, accb, sy2); }
  }
  __syncthreads();
  qpl[t] = sy;
  __syncthreads();
  if (t < 64) {
    double s = 0.0;
    for (int r = 0; r < 16; ++r) s += qpl[c0 + 64 * r];
    const size_t pi = (size_t)blockIdx.x * 128 + c0;
    psum[pi] = (round == 0) ? s : psum[pi] + s;
  }
  __syncthreads();
  qpl[t] = sy2;
  __syncthreads();
  if (t < 64) {
    double s = 0.0;
    for (int r = 0; r < 16; ++r) s += qpl[c0 + 64 * r];
    const size_t pi = (size_t)blockIdx.x * 128 + 64 + c0;
    psum[pi] = (round == 0) ? s : psum[pi] + s;
  }
}

// ---------------- graph-norm parameters ----------------
__global__ void k_norm_params(const double* __restrict__ psum,
                              const float* __restrict__ gamma, const float* __restrict__ beta,
                              const float* __restrict__ alpha, double* __restrict__ nparam) {
  const int t = threadIdx.x;
  __shared__ double m1l[64], m2l[64];
  if (t < 64) {
    double s = 0, c = 0;
    for (int b = 0; b < NBY; ++b) kah(s, c, psum[(size_t)b * 128 + t]);
    m1l[t] = s - c;
  } else if (t < 128) {
    const int ci = t - 64;
    double s = 0, c = 0;
    for (int b = 0; b < NBY; ++b) kah(s, c, psum[(size_t)b * 128 + 64 + ci]);
    m2l[ci] = s - c;
  }
  __syncthreads();
  if (t < 64) {
    const double mu = m1l[t] / (double)N;
    const double m2 = m2l[t] / (double)N;
    const double al = (double)alpha[t];
    double var = m2 - (2.0 * al - al * al) * mu * mu;
    if (var < 0.0) var = 0.0;
    nparam[t]       = al * mu;
    nparam[64 + t]  = (double)gamma[t] / sqrt(var + EPSN);
    nparam[128 + t] = (double)beta[t];
  }
}

// ---------------- final normalize -> f32 output (layer 3 only) ----------------
__global__ void k_normalize(const double* __restrict__ yv, const double* __restrict__ nparam,
                            float* __restrict__ out) {
  const int total = N * C;
  for (int i = blockIdx.x * blockDim.x + threadIdx.x; i < total; i += gridDim.x * blockDim.x) {
    const int c = i & 63;
    out[i] = (float)((yv[i] - nparam[c]) * nparam[64 + c] + nparam[128 + c]);
  }
}

}  // namespace

extern "C" void kernel_launch(void* const* d_in, const int* in_sizes, int n_in,
                              void* d_out, int out_size, void* d_ws, size_t ws_size,
                              hipStream_t stream) {
  const float* patch = (const float*)d_in[0];
  // d_in[1] edge_index, d_in[2] edge_attr: unused by the reference
  const float* Wq = (const float*)d_in[3];
  const float* Wk = (const float*)d_in[4];
  const float* Wv = (const float*)d_in[5];
  const float* Wo = (const float*)d_in[6];
  const float* bq = (const float*)d_in[7];
  const float* bk = (const float*)d_in[8];
  const float* bv = (const float*)d_in[9];
  const float* bo = (const float*)d_in[10];
  const float* P  = (const float*)d_in[11];
  const float* ga = (const float*)d_in[12];
  const float* be = (const float*)d_in[13];
  const float* al = (const float*)d_in[14];
  float* out = (float*)d_out;

  // workspace (doubles): ~58.1 MB
  double* ws      = (double*)d_ws;
  double* y       = ws;                                   // N*C          = 3.2e6
  double* partial = y + (size_t)N * C;                    // 768*2016     = 1.548e6
  double* ksumg   = partial + (size_t)(H * NB2) * PSTR;   // 240
  double* Gg      = ksumg + (size_t)H * M;                // 15360
  double* wpd     = Gg + (size_t)H * M * 64;              // 2*8*30*64    = 30720
  double* bpd     = wpd + 30720;                          // 480
  double* qpq     = bpd + 480;                            // RNODES*240   = 2.4e6
  double* psum    = qpq + (size_t)RNODES * 240;           // 512*128      = 65536
  double* nparam  = psum + (size_t)NBY * 128;             // 192

  for (int L = 0; L < 3; ++L) {
    const float* wq  = Wq + (size_t)L * C * HD;
    const float* wk  = Wk + (size_t)L * C * HD;
    const float* wv  = Wv + (size_t)L * C * HD;
    const float* wo  = Wo + (size_t)L * HD * C;
    const float* bq_ = bq + (size_t)L * HD;
    const float* bk_ = bk + (size_t)L * HD;
    const float* bv_ = bv + (size_t)L * HD;
    const float* bo_ = bo + (size_t)L * C;
    const float* p   = P  + (size_t)L * M * C;
    const int leaky = (L < 2) ? 1 : 0;

    k_wp<<<16, 256, 0, stream>>>(wk, bk_, wq, bq_, p, wpd, bpd);

    if (L == 0)
      k_kv<0><<<H * NB2, 256, 0, stream>>>(patch, nullptr, nparam, wk, bk_, wv, bv_,
                                           wpd, bpd, partial);
    else
      k_kv<1><<<H * NB2, 256, 0, stream>>>(nullptr, y, nparam, wk, bk_, wv, bv_,
                                           wpd, bpd, partial);

    k_redkv<<<H, 256, 0, stream>>>(partial, wo, ksumg, Gg);

    for (int r = 0; r < ROUNDS; ++r) {
      const int rbase = r * RNODES;
      if (L == 0)
        k_q<0><<<H * NBQH, 256, 0, stream>>>(patch, nullptr, nparam, wq, bq_,
                                             wpd, bpd, ksumg, qpq, rbase);
      else
        k_q<1><<<H * NBQH, 256, 0, stream>>>(nullptr, y, nparam, wq, bq_,
                                             wpd, bpd, ksumg, qpq, rbase);
      k_y<<<NBY, 1024, (15360 + 3840) * sizeof(double), stream>>>(
          qpq, Gg, bo_, leaky, y, psum, rbase, r);
    }

    k_norm_params<<<1, 128, 0, stream>>>(psum, ga + (size_t)L * C, be + (size_t)L * C,
                                         al + (size_t)L * C, nparam);
    if (L == 2)
      k_normalize<<<512, 256, 0, stream>>>(y, nparam, out);
  }
}

// Round 6
// 3280.331 us; speedup vs baseline: 1.8462x; 1.8462x over previous
//
#include <hip/hip_runtime.h>
#include <math.h>

// NodeformerProcessor: 3x (nodeformer_conv -> [leaky] -> graph_norm).
// v6: mixed precision, justified by error propagation (absmax was bit-stable
//     2.489675e-14 across five fp64 reorderings, so fp64 noise is far below
//     the dominant error):
//     - K-side (k_kv, partials, A/Es/Sv) fully fp32: relative errors there
//       scale the output signal by the same factor -> ~2e-17 output error.
//     - Q-side fp32 up to the exp ARGUMENT (proj-for-diag, dd, stab);
//       fp64 from exp onward (qp', den, qp'@G, y) -- f32 qp' would quantize
//       the 7e-7-relative layer-3 signal at 6e-8 (8.6%) and fail.
//     - k_y eliminated: each per-head k_q applies its G slice (f64 LDS) and
//       RMW-accumulates y across 8 sequential dispatches (h0 init, h7 fin).
//     All reductions fixed-order, no atomics; ws ~50 MB.

namespace {

constexpr int N    = 50000;
constexpr int C    = 64;
constexpr int H    = 8;
constexpr int HD   = 512;
constexpr int M    = 30;

constexpr int NB2  = 160;            // k_kv blocks/head -> grid 1280 (5/CU)
constexpr int NGRP = N / 8;          // 6250 groups of 8 nodes
constexpr int NBQ  = 1280;           // k_q grid (per head dispatch)
constexpr int PSTR = 2016;           // f32 partial: A[0,1920) Es@1920 Sv@1950 max@2014

__device__ constexpr double DN    = 0.35355339059327373;  // 1/sqrt(sqrt(64))
__device__ constexpr double RATIO = 0.18257418583505536;  // 1/sqrt(30)
__device__ constexpr double EPSK  = 1e-6;
__device__ constexpr double EPSN  = 1e-5;

__device__ __forceinline__ void kah(double& s, double& c, double v) {
  double y = v - c; double t = s + y; c = (t - s) - y; s = t;
}

// ------ pass 0: WP = DN * W @ P^T (f32 out), bp = DN * b @ P^T ---------------
__global__ __launch_bounds__(256)
void k_wp(const float* __restrict__ Wk, const float* __restrict__ bk,
          const float* __restrict__ Wq, const float* __restrict__ bq,
          const float* __restrict__ P, float* __restrict__ wp,
          float* __restrict__ bp) {
  const int blk = blockIdx.x, side = blk >> 3, h = blk & 7, t = threadIdx.x;
  const float* W  = side ? Wq : Wk;
  const float* bb = side ? bq : bk;
  for (int s = t; s < 1920; s += 256) {
    const int m = s >> 6, c = s & 63;
    double a = 0.0;
    for (int d = 0; d < 64; ++d)
      a = fma((double)W[c * HD + h * 64 + d], (double)P[m * 64 + d], a);
    wp[((size_t)(side * 8 + h) * 30 + m) * 64 + c] = (float)(a * DN);
  }
  if (t < 30) {
    double a = 0.0;
    for (int d = 0; d < 64; ++d)
      a = fma((double)bb[h * 64 + d], (double)P[t * 64 + d], a);
    bp[(side * 8 + h) * 30 + t] = (float)(a * DN);
  }
}

// ------ pass 1 (f32): per-head A/Es/Sv partials + max(dd_k) ------------------
__global__ __launch_bounds__(256, 5)
void k_kv(const float* __restrict__ x32,
          const float* __restrict__ Wk, const float* __restrict__ bk,
          const float* __restrict__ Wv, const float* __restrict__ bv,
          const float* __restrict__ wp, const float* __restrict__ bp,
          float* __restrict__ partial) {
  __shared__ float wvs[4096];        // Wv slice [c][j] for this head
  __shared__ float wpk[30 * 65];     // WP_k rows, padded
  __shared__ float xs[8 * 65];       // x rows, padded (also final scratch)
  __shared__ float vsd[8 * 65];      // v rows, padded (also final scratch)
  __shared__ float kplV[240];        // E = exp(dd - diag)
  __shared__ float diag[8];
  __shared__ float bpk[30];
  const int t = threadIdx.x, i0 = t >> 6, c0 = t & 63;
  const int h = blockIdx.x / NB2, b = blockIdx.x % NB2, hb = h * 64;

  for (int s = t; s < 4096; s += 256)
    wvs[s] = Wv[(s >> 6) * HD + hb + (s & 63)];
  for (int s = t; s < 1920; s += 256)
    wpk[(s / 64) * 65 + (s & 63)] = wp[(size_t)h * 1920 + s];
  if (t < 30) bpk[t] = bp[h * 30 + t];
  const float bk0 = bk[hb + c0], bv0 = bv[hb + c0];
  float acc8[8];
#pragma unroll
  for (int k = 0; k < 8; ++k) acc8[k] = 0.0f;
  float ssv = 0.0f, ses = 0.0f, runmax = -3.0e38f;
  const int di = (t < 240) ? t / 30 : 0;
  const int dm = (t < 240) ? t - di * 30 : 0;
  __syncthreads();

  for (int g = b; g < NGRP; g += NB2) {
    const int n0 = g * 8;
    __syncthreads();  // protect xs/vsd/kplV reuse
    xs[i0 * 65 + c0]       = x32[(size_t)(n0 + i0) * C + c0];
    xs[(i0 + 4) * 65 + c0] = x32[(size_t)(n0 + i0 + 4) * C + c0];
    __syncthreads();
    // k,v projection (f32): 2 nodes/thread, 8 independent chains
    float kaA = bk0, kaB = 0.f, k1A = bk0, k1B = 0.f;
    float vaA = bv0, vaB = 0.f, v1A = bv0, v1B = 0.f;
#pragma unroll 8
    for (int c = 0; c < 32; ++c) {
      const float x0a = xs[i0 * 65 + c],       x0b = xs[i0 * 65 + c + 32];
      const float x1a = xs[(i0 + 4) * 65 + c], x1b = xs[(i0 + 4) * 65 + c + 32];
      const float wka = Wk[c * HD + hb + c0];
      const float wkb = Wk[(c + 32) * HD + hb + c0];
      const float wva = wvs[c * 64 + c0];
      const float wvb = wvs[(c + 32) * 64 + c0];
      kaA = fmaf(x0a, wka, kaA); kaB = fmaf(x0b, wkb, kaB);
      k1A = fmaf(x1a, wka, k1A); k1B = fmaf(x1b, wkb, k1B);
      vaA = fmaf(x0a, wva, vaA); vaB = fmaf(x0b, wvb, vaB);
      v1A = fmaf(x1a, wva, v1A); v1B = fmaf(x1b, wvb, v1B);
    }
    const float ka0 = kaA + kaB, ka1 = k1A + k1B;
    const float va0 = vaA + vaB, va1 = v1A + v1B;
    vsd[i0 * 65 + c0] = va0; vsd[(i0 + 4) * 65 + c0] = va1;
    float q0 = ka0 * ka0, q1 = ka1 * ka1;
#pragma unroll
    for (int off = 32; off; off >>= 1) {
      q0 += __shfl_xor(q0, off, 64);
      q1 += __shfl_xor(q1, off, 64);
    }
    if (c0 == 0) {
      diag[i0]     = q0 * (float)(DN * DN * 0.5);
      diag[i0 + 4] = q1 * (float)(DN * DN * 0.5);
    }
    ssv += va0 + va1;  // Sv[c0] partial
    __syncthreads();
    // dd_k from x via WP; track raw max; E = exp(dd - diag)
    if (t < 240) {
      float a = bpk[dm];
#pragma unroll 8
      for (int c = 0; c < 64; ++c)
        a = fmaf(xs[di * 65 + c], wpk[dm * 65 + c], a);
      runmax = fmaxf(runmax, a);
      kplV[t] = __expf(a - diag[di]);
    }
    __syncthreads();
    if (t < 30) {
      float gsum = 0.0f;
#pragma unroll
      for (int i = 0; i < 8; ++i) gsum += kplV[i * 30 + t];
      ses += gsum;
    }
#pragma unroll
    for (int k = 0; k < 8; ++k) {
      const int s = t + (k << 8);
      if (s < 1920) {
        const int m = s >> 6;
        float gsum = acc8[k];
#pragma unroll
        for (int i = 0; i < 8; ++i)
          gsum = fmaf(kplV[i * 30 + m], vsd[i * 65 + c0], gsum);
        acc8[k] = gsum;
      }
    }
  }
  // block outputs (reuse xs/vsd as scratch)
  const size_t base = (size_t)blockIdx.x * PSTR;
  __syncthreads();
  xs[t] = ssv;
  vsd[t] = runmax;
  __syncthreads();
  if (t < 64) partial[base + 1950 + t] = xs[t] + xs[t + 64] + xs[t + 128] + xs[t + 192];
  for (int off = 128; off; off >>= 1) {
    if (t < off) vsd[t] = fmaxf(vsd[t], vsd[t + off]);
    __syncthreads();
  }
  if (t == 0) partial[base + 2014] = vsd[0];
  if (t < 30) partial[base + 1920 + t] = ses;
#pragma unroll
  for (int k = 0; k < 8; ++k) {
    const int s = t + (k << 8);
    if (s < 1920) partial[base + s] = acc8[k];
  }
}

// ------ pass 2: reduce f32 partials in f64, apply stab/eps, G = kvs@Wo ------
__global__ __launch_bounds__(256)
void k_redkv(const float* __restrict__ partial, const float* __restrict__ Wo,
             double* __restrict__ ksumg, double* __restrict__ Gg) {
  const int h = blockIdx.x, t = threadIdx.x;
  __shared__ float red[256];
  __shared__ double svt[64];
  __shared__ double kvls[M * 64];
  __shared__ double escs;
  const size_t hb = (size_t)h * NB2;
  red[t] = (t < NB2) ? partial[(hb + t) * PSTR + 2014] : -3.0e38f;
  __syncthreads();
  for (int off = 128; off; off >>= 1) {
    if (t < off) red[t] = fmaxf(red[t], red[t + off]);
    __syncthreads();
  }
  if (t == 0) escs = exp(-(double)red[0]);
  __syncthreads();
  const double esc = escs;
  if (t < 64) {
    double s = 0.0;
    for (int b = 0; b < NB2; ++b) s += (double)partial[(hb + b) * PSTR + 1950 + t];
    svt[t] = s;
  } else if (t < 64 + M) {
    const int m = t - 64;
    double s = 0.0;
    for (int b = 0; b < NB2; ++b) s += (double)partial[(hb + b) * PSTR + 1920 + m];
    ksumg[h * M + m] = RATIO * (esc * s + EPSK * (double)N);
  }
  __syncthreads();
#pragma unroll
  for (int k = 0; k < 8; ++k) {
    const int sidx = t + (k << 8);
    if (sidx < M * 64) {
      double s = 0.0;
      for (int b = 0; b < NB2; ++b) s += (double)partial[(hb + b) * PSTR + sidx];
      kvls[sidx] = RATIO * (esc * s + EPSK * svt[sidx & 63]);
    }
  }
  __syncthreads();
#pragma unroll
  for (int k = 0; k < 8; ++k) {
    const int sidx = t + (k << 8);
    if (sidx < M * 64) {
      const int m = sidx >> 6, c = sidx & 63;
      double a = 0.0;
      for (int d = 0; d < 64; ++d)
        a = fma(kvls[m * 64 + d], (double)Wo[(h * 64 + d) * 64 + c], a);
      Gg[(size_t)h * (M * 64) + sidx] = a;
    }
  }
}

// ------ pass 3 (x8 heads): f32 front -> f64 qp' -> y += qp' @ G --------------
// MODE: 0 = init (bo + contrib), 1 = add, 2 = final (add, leaky, col sums)
template <int MODE>
__global__ __launch_bounds__(256, 5)
void k_q(const float* __restrict__ x32,
         const float* __restrict__ Wq, const float* __restrict__ bq,
         const float* __restrict__ wp, const float* __restrict__ bp,
         const double* __restrict__ ksumg, const double* __restrict__ Gg,
         const float* __restrict__ bo, int do_leaky, int h,
         double* __restrict__ y, double* __restrict__ psum) {
  __shared__ float  wpq[30 * 65];
  __shared__ double gl[30 * 64];
  __shared__ float  xs[8 * 65];
  __shared__ float  qraw[240];
  __shared__ double qpd[8][30];
  __shared__ double rden[8];
  __shared__ float  diag[8];
  __shared__ double ksl[30];
  __shared__ float  bpq[30];
  __shared__ double red[256];
  const int t = threadIdx.x, i0 = t >> 6, c0 = t & 63;
  const int hb = h * 64;

  for (int s = t; s < 1920; s += 256) {
    wpq[(s / 64) * 65 + (s & 63)] = wp[(size_t)(8 + h) * 1920 + s];
    gl[s] = Gg[(size_t)h * 1920 + s];
  }
  for (int s = t + 1920; s < 1920; s += 256) {}  // (no-op, keep structure)
  if (t < 30) { bpq[t] = bp[(8 + h) * 30 + t]; ksl[t] = ksumg[h * 30 + t]; }
  const float bq0 = bq[hb + c0];
  const double bo0 = (double)bo[c0];
  const int di = (t < 240) ? t / 30 : 0;
  const int dm = (t < 240) ? t - di * 30 : 0;
  double sy = 0.0, sy2 = 0.0;
  __syncthreads();

  for (int g = blockIdx.x; g < NGRP; g += NBQ) {
    const int n0 = g * 8;
    __syncthreads();  // protect xs/qraw/qpd reuse
    xs[i0 * 65 + c0]       = x32[(size_t)(n0 + i0) * C + c0];
    xs[(i0 + 4) * 65 + c0] = x32[(size_t)(n0 + i0 + 4) * C + c0];
    __syncthreads();
    // q projection (f32, for diag only)
    float qA = bq0, qB = 0.f, q1A = bq0, q1B = 0.f;
#pragma unroll 8
    for (int c = 0; c < 32; ++c) {
      const float x0a = xs[i0 * 65 + c],       x0b = xs[i0 * 65 + c + 32];
      const float x1a = xs[(i0 + 4) * 65 + c], x1b = xs[(i0 + 4) * 65 + c + 32];
      const float wqa = Wq[c * HD + hb + c0];
      const float wqb = Wq[(c + 32) * HD + hb + c0];
      qA  = fmaf(x0a, wqa, qA);  qB  = fmaf(x0b, wqb, qB);
      q1A = fmaf(x1a, wqa, q1A); q1B = fmaf(x1b, wqb, q1B);
    }
    const float qa0 = qA + qB, qa1 = q1A + q1B;
    float s0 = qa0 * qa0, s1 = qa1 * qa1;
#pragma unroll
    for (int off = 32; off; off >>= 1) {
      s0 += __shfl_xor(s0, off, 64);
      s1 += __shfl_xor(s1, off, 64);
    }
    if (c0 == 0) {
      diag[i0]     = s0 * (float)(DN * DN * 0.5);
      diag[i0 + 4] = s1 * (float)(DN * DN * 0.5);
    }
    // dd_q (f32) from x via WP
    if (t < 240) {
      float a = bpq[dm];
#pragma unroll 8
      for (int c = 0; c < 64; ++c)
        a = fmaf(xs[di * 65 + c], wpq[dm * 65 + c], a);
      qraw[t] = a;
    }
    __syncthreads();
    // stab (per-node max over m), exp in f64
    if (t < 240) {
      float mx = qraw[di * 30];
      for (int m = 1; m < 30; ++m) mx = fmaxf(mx, qraw[di * 30 + m]);
      const float arg = (qraw[t] - diag[di]) - mx;
      qpd[di][dm] = RATIO * (exp((double)arg) + EPSK);
    }
    __syncthreads();
    if (t < 8) {
      double den = 0.0;
      for (int m = 0; m < 30; ++m) den = fma(qpd[t][m], ksl[m], den);
      rden[t] = 1.0 / den;
    }
    __syncthreads();
    // y-apply: thread -> (node i0, c0) and (node i0+4, c0)
    {
      double sa = 0.0, sb = 0.0;
      for (int m = 0; m < 30; ++m) {
        const double gv = gl[m * 64 + c0];
        sa = fma(qpd[i0][m],     gv, sa);
        sb = fma(qpd[i0 + 4][m], gv, sb);
      }
      double ca = sa * rden[i0];
      double cb = sb * rden[i0 + 4];
      const size_t ia = (size_t)(n0 + i0) * C + c0;
      const size_t ib = (size_t)(n0 + i0 + 4) * C + c0;
      if (MODE == 0) {
        y[ia] = bo0 + ca;
        y[ib] = bo0 + cb;
      } else if (MODE == 1) {
        y[ia] += ca;
        y[ib] += cb;
      } else {
        double va = y[ia] + ca, vb = y[ib] + cb;
        if (do_leaky) {
          va = (va >= 0.0) ? va : 0.01 * va;
          vb = (vb >= 0.0) ? vb : 0.01 * vb;
        }
        y[ia] = va; y[ib] = vb;
        sy += va + vb;
        sy2 = fma(va, va, sy2);
        sy2 = fma(vb, vb, sy2);
      }
    }
  }
  if (MODE == 2) {  // block column sums
    __syncthreads();
    red[t] = sy;
    __syncthreads();
    if (t < 64) psum[(size_t)blockIdx.x * 128 + t] =
        red[t] + red[t + 64] + red[t + 128] + red[t + 192];
    __syncthreads();
    red[t] = sy2;
    __syncthreads();
    if (t < 64) psum[(size_t)blockIdx.x * 128 + 64 + t] =
        red[t] + red[t + 64] + red[t + 128] + red[t + 192];
  }
}

// ------ graph-norm parameters ------------------------------------------------
__global__ void k_norm_params(const double* __restrict__ psum,
                              const float* __restrict__ gamma, const float* __restrict__ beta,
                              const float* __restrict__ alpha, double* __restrict__ nparam) {
  const int t = threadIdx.x;
  __shared__ double m1l[64], m2l[64];
  if (t < 64) {
    double s = 0, c = 0;
    for (int b = 0; b < NBQ; ++b) kah(s, c, psum[(size_t)b * 128 + t]);
    m1l[t] = s - c;
  } else if (t < 128) {
    const int ci = t - 64;
    double s = 0, c = 0;
    for (int b = 0; b < NBQ; ++b) kah(s, c, psum[(size_t)b * 128 + 64 + ci]);
    m2l[ci] = s - c;
  }
  __syncthreads();
  if (t < 64) {
    const double mu = m1l[t] / (double)N;
    const double m2 = m2l[t] / (double)N;
    const double al = (double)alpha[t];
    double var = m2 - (2.0 * al - al * al) * mu * mu;
    if (var < 0.0) var = 0.0;
    nparam[t]       = al * mu;
    nparam[64 + t]  = (double)gamma[t] / sqrt(var + EPSN);
    nparam[128 + t] = (double)beta[t];
  }
}

// ------ normalize y -> f32 (next-layer x32, or final output) -----------------
__global__ void k_cast(const double* __restrict__ yv, const double* __restrict__ nparam,
                       float* __restrict__ dst) {
  const int total = N * C;
  for (int i = blockIdx.x * blockDim.x + threadIdx.x; i < total; i += gridDim.x * blockDim.x) {
    const int c = i & 63;
    dst[i] = (float)((yv[i] - nparam[c]) * nparam[64 + c] + nparam[128 + c]);
  }
}

}  // namespace

extern "C" void kernel_launch(void* const* d_in, const int* in_sizes, int n_in,
                              void* d_out, int out_size, void* d_ws, size_t ws_size,
                              hipStream_t stream) {
  const float* patch = (const float*)d_in[0];
  // d_in[1] edge_index, d_in[2] edge_attr: unused by the reference
  const float* Wq = (const float*)d_in[3];
  const float* Wk = (const float*)d_in[4];
  const float* Wv = (const float*)d_in[5];
  const float* Wo = (const float*)d_in[6];
  const float* bq = (const float*)d_in[7];
  const float* bk = (const float*)d_in[8];
  const float* bv = (const float*)d_in[9];
  const float* bo = (const float*)d_in[10];
  const float* P  = (const float*)d_in[11];
  const float* ga = (const float*)d_in[12];
  const float* be = (const float*)d_in[13];
  const float* al = (const float*)d_in[14];
  float* out = (float*)d_out;

  // workspace layout (~50 MB)
  char* wsb = (char*)d_ws;
  double* y      = (double*)wsb;                 wsb += (size_t)N * C * 8;      // 25.6MB
  double* Gg     = (double*)wsb;                 wsb += (size_t)H * M * 64 * 8; // 123KB
  double* ksumg  = (double*)wsb;                 wsb += (size_t)H * M * 8;
  double* psum   = (double*)wsb;                 wsb += (size_t)NBQ * 128 * 8;  // 1.3MB
  double* nparam = (double*)wsb;                 wsb += 192 * 8;
  float*  x32    = (float*)wsb;                  wsb += (size_t)N * C * 4;      // 12.8MB
  float*  partial= (float*)wsb;                  wsb += (size_t)(H * NB2) * PSTR * 4; // 10.3MB
  float*  wpf    = (float*)wsb;                  wsb += 30720 * 4;              // 123KB
  float*  bpf    = (float*)wsb;                  wsb += 480 * 4;

  for (int L = 0; L < 3; ++L) {
    const float* wq  = Wq + (size_t)L * C * HD;
    const float* wk  = Wk + (size_t)L * C * HD;
    const float* wv  = Wv + (size_t)L * C * HD;
    const float* wo  = Wo + (size_t)L * HD * C;
    const float* bq_ = bq + (size_t)L * HD;
    const float* bk_ = bk + (size_t)L * HD;
    const float* bv_ = bv + (size_t)L * HD;
    const float* bo_ = bo + (size_t)L * C;
    const float* p   = P  + (size_t)L * M * C;
    const int leaky = (L < 2) ? 1 : 0;
    const float* xcur = (L == 0) ? patch : x32;

    k_wp<<<16, 256, 0, stream>>>(wk, bk_, wq, bq_, p, wpf, bpf);

    k_kv<<<H * NB2, 256, 0, stream>>>(xcur, wk, bk_, wv, bv_, wpf, bpf, partial);
    k_redkv<<<H, 256, 0, stream>>>(partial, wo, ksumg, Gg);

    k_q<0><<<NBQ, 256, 0, stream>>>(xcur, wq, bq_, wpf, bpf, ksumg, Gg, bo_,
                                    leaky, 0, y, psum);
    for (int h = 1; h < 7; ++h)
      k_q<1><<<NBQ, 256, 0, stream>>>(xcur, wq, bq_, wpf, bpf, ksumg, Gg, bo_,
                                      leaky, h, y, psum);
    k_q<2><<<NBQ, 256, 0, stream>>>(xcur, wq, bq_, wpf, bpf, ksumg, Gg, bo_,
                                    leaky, 7, y, psum);

    k_norm_params<<<1, 128, 0, stream>>>(psum, ga + (size_t)L * C, be + (size_t)L * C,
                                         al + (size_t)L * C, nparam);
    k_cast<<<512, 256, 0, stream>>>(y, nparam, (L < 2) ? x32 : out);
  }
}